// Round 1
// baseline (1100.090 us; speedup 1.0000x reference)
//
#include <hip/hip_runtime.h>

#define NN 50000
#define NE 800000
#define DD 256
#define EPSV 1e-5f

// ---------------- CSR build (by dst) ----------------

__global__ void deg_count_k(const int* __restrict__ ei, int* __restrict__ deg) {
  int e = blockIdx.x * 256 + threadIdx.x;
  if (e < NE) atomicAdd(&deg[ei[NE + e]], 1);
}

__global__ void scan1_k(const int* __restrict__ deg, int* __restrict__ row_ptr,
                        int* __restrict__ blockSums) {
  __shared__ int s[1024];
  int gid = blockIdx.x * 1024 + threadIdx.x;
  int v = (gid < NN) ? deg[gid] : 0;
  s[threadIdx.x] = v;
  __syncthreads();
  for (int off = 1; off < 1024; off <<= 1) {
    int t = (threadIdx.x >= off) ? s[threadIdx.x - off] : 0;
    __syncthreads();
    s[threadIdx.x] += t;
    __syncthreads();
  }
  if (gid < NN) row_ptr[gid] = s[threadIdx.x] - v;  // exclusive within block
  if (threadIdx.x == 1023) blockSums[blockIdx.x] = s[1023];
}

__global__ void scan2_k(const int* __restrict__ blockSums, int* __restrict__ blockOffs,
                        int* __restrict__ row_ptr, int nblocks) {
  if (threadIdx.x == 0) {
    int run = 0;
    for (int i = 0; i < nblocks; ++i) { blockOffs[i] = run; run += blockSums[i]; }
    row_ptr[NN] = run;  // == NE
  }
}

__global__ void scan3_k(int* __restrict__ row_ptr, const int* __restrict__ blockOffs,
                        const int* __restrict__ deg, float* __restrict__ deg_inv) {
  int gid = blockIdx.x * 1024 + threadIdx.x;
  if (gid < NN) {
    row_ptr[gid] += blockOffs[blockIdx.x];
    deg_inv[gid] = 1.0f / (float)max(deg[gid], 1);
  }
}

__global__ void csr_fill_k(const int* __restrict__ ei, int* __restrict__ cursor,
                           int* __restrict__ col_idx) {
  int e = blockIdx.x * 256 + threadIdx.x;
  if (e < NE) {
    int pos = atomicAdd(&cursor[ei[NE + e]], 1);
    col_idx[pos] = ei[e];  // src
  }
}

// ---------------- aggregation: one wave per node ----------------
// 64 lanes x float4 = one full 256-float row per iteration, coalesced 1KB reads.

__global__ __launch_bounds__(256) void sage_agg_k(
    const float* __restrict__ h, const int* __restrict__ row_ptr,
    const int* __restrict__ col_idx, const float* __restrict__ deg_inv,
    float* __restrict__ agg) {
  int wave = threadIdx.x >> 6;
  int lane = threadIdx.x & 63;
  int node = blockIdx.x * 4 + wave;  // grid = 12500 * 4 waves = 50000 exactly
  int beg = row_ptr[node], end = row_ptr[node + 1];
  float ax = 0.f, ay = 0.f, az = 0.f, aw = 0.f;
  for (int e = beg; e < end; ++e) {
    int srcn = col_idx[e];
    float4 v = *reinterpret_cast<const float4*>(h + (size_t)srcn * DD + lane * 4);
    ax += v.x; ay += v.y; az += v.z; aw += v.w;
  }
  float di = deg_inv[node];
  float4 o = make_float4(ax * di, ay * di, az * di, aw * di);
  *reinterpret_cast<float4*>(agg + (size_t)node * DD + lane * 4) = o;
}

// ---------------- fused GEMM: out = agg@Wl + h@Wr + b (+BN+ReLU+residual) ----------------
// Treated as [agg | h] (M x 512) @ [Wl ; Wr] (512 x 256).
// 64x64 tile, 4x4 micro-tile, BK=16.

template <bool DO_BN>
__global__ __launch_bounds__(256) void sage_gemm_k(
    const float* __restrict__ Aagg, const float* __restrict__ Ah,
    const float* __restrict__ Wl, const float* __restrict__ Wr,
    const float* __restrict__ bias,
    const float* __restrict__ gamma, const float* __restrict__ beta,
    const float* __restrict__ mean, const float* __restrict__ var,
    float* __restrict__ out) {
  __shared__ float As[16][68];  // [k][m], padded: rows 16B-aligned, b128-friendly
  __shared__ float Bs[16][68];  // [k][n]

  int tx = threadIdx.x & 15;   // n direction
  int ty = threadIdx.x >> 4;   // m direction
  int m0 = blockIdx.x * 64;
  int n0 = blockIdx.y * 64;

  // A-load mapping: thread -> (row, 4 k-cols)
  int la_m = threadIdx.x >> 2;        // 0..63
  int la_k = (threadIdx.x & 3) * 4;   // 0,4,8,12
  // B-load mapping: thread -> (k-row, 4 n-cols)
  int lb_k = threadIdx.x >> 4;        // 0..15
  int lb_n = (threadIdx.x & 15) * 4;  // 0..60

  float acc[4][4] = {};

  for (int kt = 0; kt < 32; ++kt) {
    int kbase = kt * 16;
    const float* Asrc = (kbase < 256) ? Aagg : Ah;
    const float* Bsrc = (kbase < 256) ? Wl : Wr;
    int krow = kbase & 255;

    float4 av = make_float4(0.f, 0.f, 0.f, 0.f);
    int gm = m0 + la_m;
    if (gm < NN)
      av = *reinterpret_cast<const float4*>(Asrc + (size_t)gm * DD + krow + la_k);
    As[la_k + 0][la_m] = av.x;
    As[la_k + 1][la_m] = av.y;
    As[la_k + 2][la_m] = av.z;
    As[la_k + 3][la_m] = av.w;

    float4 bv = *reinterpret_cast<const float4*>(Bsrc + (size_t)(krow + lb_k) * DD + n0 + lb_n);
    *reinterpret_cast<float4*>(&Bs[lb_k][lb_n]) = bv;

    __syncthreads();
#pragma unroll
    for (int k = 0; k < 16; ++k) {
      float a[4], b[4];
#pragma unroll
      for (int i = 0; i < 4; ++i) a[i] = As[k][ty * 4 + i];
#pragma unroll
      for (int j = 0; j < 4; ++j) b[j] = Bs[k][tx * 4 + j];
#pragma unroll
      for (int i = 0; i < 4; ++i)
#pragma unroll
        for (int j = 0; j < 4; ++j) acc[i][j] = fmaf(a[i], b[j], acc[i][j]);
    }
    __syncthreads();
  }

  // epilogue
  float bb[4], sc[4], sh[4];
#pragma unroll
  for (int j = 0; j < 4; ++j) {
    int n = n0 + tx * 4 + j;
    bb[j] = bias[n];
    if (DO_BN) {
      float s = gamma[n] * rsqrtf(var[n] + EPSV);
      sc[j] = s;
      sh[j] = beta[n] - mean[n] * s;
    }
  }
#pragma unroll
  for (int i = 0; i < 4; ++i) {
    int m = m0 + ty * 4 + i;
    if (m < NN) {
      float o[4];
      if (DO_BN) {
        float4 r = *reinterpret_cast<const float4*>(Ah + (size_t)m * DD + n0 + tx * 4);
        float rr[4] = {r.x, r.y, r.z, r.w};
#pragma unroll
        for (int j = 0; j < 4; ++j) {
          float v = acc[i][j] + bb[j];
          v = v * sc[j] + sh[j];     // BN (inference)
          v = fmaxf(v, 0.f);         // ReLU
          o[j] = v + rr[j];          // residual
        }
      } else {
#pragma unroll
        for (int j = 0; j < 4; ++j) o[j] = acc[i][j] + bb[j];
      }
      *reinterpret_cast<float4*>(out + (size_t)m * DD + n0 + tx * 4) =
          make_float4(o[0], o[1], o[2], o[3]);
    }
  }
}

// ---------------- launch ----------------

extern "C" void kernel_launch(void* const* d_in, const int* in_sizes, int n_in,
                              void* d_out, int out_size, void* d_ws, size_t ws_size,
                              hipStream_t stream) {
  const float* x   = (const float*)d_in[0];
  const int*   ei  = (const int*)d_in[1];
  const float* Wl[3] = {(const float*)d_in[2], (const float*)d_in[5], (const float*)d_in[8]};
  const float* Wr[3] = {(const float*)d_in[3], (const float*)d_in[6], (const float*)d_in[9]};
  const float* bs[3] = {(const float*)d_in[4], (const float*)d_in[7], (const float*)d_in[10]};
  const float* g0  = (const float*)d_in[11];
  const float* be0 = (const float*)d_in[12];
  const float* mu0 = (const float*)d_in[13];
  const float* va0 = (const float*)d_in[14];
  const float* g1  = (const float*)d_in[15];
  const float* be1 = (const float*)d_in[16];
  const float* mu1 = (const float*)d_in[17];
  const float* va1 = (const float*)d_in[18];
  float* out = (float*)d_out;

  char* w = (char*)d_ws;
  // packed workspace layout (bytes)
  const size_t o_deg    = 0;                       // NN ints
  const size_t o_rowptr = 262144;                  // NN+1 ints
  const size_t o_cursor = 524288;                  // NN ints
  const size_t o_colidx = 786432;                  // NE ints (3.2 MB)
  const size_t o_deginv = 4194304;                 // NN floats
  const size_t o_bsum   = 4456448;                 // scan partials
  const size_t o_boff   = 4460544;
  const size_t o_agg    = 4464640;                 // NN*DD floats (51.2 MB)
  const size_t o_bufA   = o_agg  + 51200000;       // NN*DD floats
  const size_t o_bufB   = o_bufA + 51200000;       // NN*DD floats
  // total ~158 MB

  int*   deg     = (int*)(w + o_deg);
  int*   row_ptr = (int*)(w + o_rowptr);
  int*   cursor  = (int*)(w + o_cursor);
  int*   col_idx = (int*)(w + o_colidx);
  float* deg_inv = (float*)(w + o_deginv);
  int*   bsum    = (int*)(w + o_bsum);
  int*   boff    = (int*)(w + o_boff);
  float* agg     = (float*)(w + o_agg);
  float* bufA    = (float*)(w + o_bufA);
  float* bufB    = (float*)(w + o_bufB);

  const int SCAN_BLOCKS = (NN + 1023) / 1024;  // 49

  // ---- CSR build (once per call; reused by all 3 layers) ----
  hipMemsetAsync(deg, 0, NN * sizeof(int), stream);
  deg_count_k<<<NE / 256, 256, 0, stream>>>(ei, deg);
  scan1_k<<<SCAN_BLOCKS, 1024, 0, stream>>>(deg, row_ptr, bsum);
  scan2_k<<<1, 64, 0, stream>>>(bsum, boff, row_ptr, SCAN_BLOCKS);
  scan3_k<<<SCAN_BLOCKS, 1024, 0, stream>>>(row_ptr, boff, deg, deg_inv);
  hipMemcpyAsync(cursor, row_ptr, NN * sizeof(int), hipMemcpyDeviceToDevice, stream);
  csr_fill_k<<<NE / 256, 256, 0, stream>>>(ei, cursor, col_idx);

  dim3 ggrid((NN + 63) / 64, 4);  // 782 x 4

  // ---- layer 0: x -> bufA ----
  sage_agg_k<<<NN / 4, 256, 0, stream>>>(x, row_ptr, col_idx, deg_inv, agg);
  sage_gemm_k<true><<<ggrid, 256, 0, stream>>>(agg, x, Wl[0], Wr[0], bs[0],
                                               g0, be0, mu0, va0, bufA);
  // ---- layer 1: bufA -> bufB ----
  sage_agg_k<<<NN / 4, 256, 0, stream>>>(bufA, row_ptr, col_idx, deg_inv, agg);
  sage_gemm_k<true><<<ggrid, 256, 0, stream>>>(agg, bufA, Wl[1], Wr[1], bs[1],
                                               g1, be1, mu1, va1, bufB);
  // ---- layer 2: bufB -> out ----
  sage_agg_k<<<NN / 4, 256, 0, stream>>>(bufB, row_ptr, col_idx, deg_inv, agg);
  sage_gemm_k<false><<<ggrid, 256, 0, stream>>>(agg, bufB, Wl[2], Wr[2], bs[2],
                                                nullptr, nullptr, nullptr, nullptr, out);
}

// Round 2
// 926.693 us; speedup vs baseline: 1.1871x; 1.1871x over previous
//
#include <hip/hip_runtime.h>
#include <hip/hip_bf16.h>

#define NN 50000
#define NE 800000
#define DD 256
#define EPSV 1e-5f

typedef float f32x4 __attribute__((ext_vector_type(4)));
typedef short bf16x8s __attribute__((ext_vector_type(8)));  // 8 bf16 payload = 4 VGPR

__device__ __forceinline__ float bf2f(unsigned short u) {
  unsigned int x = ((unsigned int)u) << 16;
  return __builtin_bit_cast(float, x);
}
__device__ __forceinline__ unsigned short f2bf(float f) {
  return __builtin_bit_cast(unsigned short, __float2bfloat16(f));
}

// D = A(16x32) * B(32x16) + C ; A row=lane&15 k=8*(lane>>4)+j ; B col=lane&15 same k ;
// C/D col=lane&15 row=4*(lane>>4)+reg   (guide §3, m89/m91-verified)
__device__ __forceinline__ void mfma_bf16(bf16x8s a, bf16x8s b, f32x4& c) {
  asm("v_mfma_f32_16x16x32_bf16 %0, %1, %2, %0" : "+v"(c) : "v"(a), "v"(b));
}

__device__ __forceinline__ void gload_lds16(const void* g, void* l) {
  __builtin_amdgcn_global_load_lds((const __attribute__((address_space(1))) void*)g,
                                   (__attribute__((address_space(3))) void*)l, 16, 0, 0);
}

// ---------------- CSR build (by dst) ----------------

__global__ void deg_count_k(const int* __restrict__ ei, int* __restrict__ deg) {
  int e = blockIdx.x * 256 + threadIdx.x;
  if (e < NE) atomicAdd(&deg[ei[NE + e]], 1);
}

__global__ void scan1_k(const int* __restrict__ deg, int* __restrict__ row_ptr,
                        int* __restrict__ blockSums) {
  __shared__ int s[1024];
  int gid = blockIdx.x * 1024 + threadIdx.x;
  int v = (gid < NN) ? deg[gid] : 0;
  s[threadIdx.x] = v;
  __syncthreads();
  for (int off = 1; off < 1024; off <<= 1) {
    int t = (threadIdx.x >= off) ? s[threadIdx.x - off] : 0;
    __syncthreads();
    s[threadIdx.x] += t;
    __syncthreads();
  }
  if (gid < NN) row_ptr[gid] = s[threadIdx.x] - v;
  if (threadIdx.x == 1023) blockSums[blockIdx.x] = s[1023];
}

__global__ void scan2_k(const int* __restrict__ blockSums, int* __restrict__ blockOffs,
                        int* __restrict__ row_ptr, int nblocks) {
  if (threadIdx.x == 0) {
    int run = 0;
    for (int i = 0; i < nblocks; ++i) { blockOffs[i] = run; run += blockSums[i]; }
    row_ptr[NN] = run;
  }
}

__global__ void scan3_k(int* __restrict__ row_ptr, const int* __restrict__ blockOffs,
                        const int* __restrict__ deg, float* __restrict__ deg_inv) {
  int gid = blockIdx.x * 1024 + threadIdx.x;
  if (gid < NN) {
    row_ptr[gid] += blockOffs[blockIdx.x];
    deg_inv[gid] = 1.0f / (float)max(deg[gid], 1);
  }
}

__global__ void csr_fill_k(const int* __restrict__ ei, int* __restrict__ cursor,
                           int* __restrict__ col_idx) {
  int e = blockIdx.x * 256 + threadIdx.x;
  if (e < NE) {
    int pos = atomicAdd(&cursor[ei[NE + e]], 1);
    col_idx[pos] = ei[e];
  }
}

// ---------------- x -> hi/lo bf16 planes ----------------

__global__ __launch_bounds__(256) void split_x_k(const float* __restrict__ x,
                                                 unsigned short* __restrict__ xhi,
                                                 unsigned short* __restrict__ xlo) {
  int gid = blockIdx.x * 256 + threadIdx.x;  // 3.2M threads, 4 elems each
  float4 v = reinterpret_cast<const float4*>(x)[gid];
  float f[4] = {v.x, v.y, v.z, v.w};
  ushort4 hi, lo;
  unsigned short* hp = &hi.x; unsigned short* lp = &lo.x;
#pragma unroll
  for (int c = 0; c < 4; ++c) {
    unsigned short h = f2bf(f[c]);
    hp[c] = h;
    lp[c] = f2bf(f[c] - bf2f(h));
  }
  reinterpret_cast<ushort4*>(xhi)[gid] = hi;
  reinterpret_cast<ushort4*>(xlo)[gid] = lo;
}

// ---------------- W (din x dout, k-major) -> W^T hi/lo bf16 (n x k) ----------------

__global__ __launch_bounds__(256) void wtprep_k(const float* __restrict__ W,
                                                unsigned short* __restrict__ thi,
                                                unsigned short* __restrict__ tlo) {
  int gid = blockIdx.x * 256 + threadIdx.x;  // 16384 = 256 n * 64 k-quads
  int n = gid >> 6, k4 = (gid & 63) << 2;
  ushort4 hi, lo;
  unsigned short* hp = &hi.x; unsigned short* lp = &lo.x;
#pragma unroll
  for (int r = 0; r < 4; ++r) {
    float v = W[(size_t)(k4 + r) * DD + n];
    unsigned short h = f2bf(v);
    hp[r] = h;
    lp[r] = f2bf(v - bf2f(h));
  }
  *reinterpret_cast<ushort4*>(thi + (size_t)n * DD + k4) = hi;
  *reinterpret_cast<ushort4*>(tlo + (size_t)n * DD + k4) = lo;
}

// ---------------- aggregation: one wave per node, hi/lo reconstruct ----------------

__global__ __launch_bounds__(256) void sage_agg_k(
    const unsigned short* __restrict__ hhi, const unsigned short* __restrict__ hlo,
    const int* __restrict__ row_ptr, const int* __restrict__ col_idx,
    const float* __restrict__ deg_inv,
    unsigned short* __restrict__ ahi, unsigned short* __restrict__ alo) {
  int wave = threadIdx.x >> 6;
  int lane = threadIdx.x & 63;
  int node = blockIdx.x * 4 + wave;
  int beg = row_ptr[node], end = row_ptr[node + 1];
  float a0 = 0.f, a1 = 0.f, a2 = 0.f, a3 = 0.f;
  for (int e = beg; e < end; ++e) {
    int s = col_idx[e];
    ushort4 vh = *(reinterpret_cast<const ushort4*>(hhi + (size_t)s * DD) + lane);
    ushort4 vl = *(reinterpret_cast<const ushort4*>(hlo + (size_t)s * DD) + lane);
    a0 += bf2f(vh.x) + bf2f(vl.x);
    a1 += bf2f(vh.y) + bf2f(vl.y);
    a2 += bf2f(vh.z) + bf2f(vl.z);
    a3 += bf2f(vh.w) + bf2f(vl.w);
  }
  float di = deg_inv[node];
  float f[4] = {a0 * di, a1 * di, a2 * di, a3 * di};
  ushort4 hi, lo;
  unsigned short* hp = &hi.x; unsigned short* lp = &lo.x;
#pragma unroll
  for (int c = 0; c < 4; ++c) {
    unsigned short h = f2bf(f[c]);
    hp[c] = h;
    lp[c] = f2bf(f[c] - bf2f(h));
  }
  *(reinterpret_cast<ushort4*>(ahi + (size_t)node * DD) + lane) = hi;
  *(reinterpret_cast<ushort4*>(alo + (size_t)node * DD) + lane) = lo;
}

// ---------------- MFMA GEMM: out = [agg|h] @ [Wl;Wr] + b (+BN+ReLU+residual) ----------------
// 128x128 tile, BK=32, 4 waves (2x2), fragment-linear LDS, 3-product hi/lo exact split.

template <bool DO_BN>
__global__ __launch_bounds__(256) void sage_gemm_k(
    const unsigned short* __restrict__ aHi, const unsigned short* __restrict__ aLo,
    const unsigned short* __restrict__ hHi, const unsigned short* __restrict__ hLo,
    const unsigned short* __restrict__ wlHi, const unsigned short* __restrict__ wlLo,
    const unsigned short* __restrict__ wrHi, const unsigned short* __restrict__ wrLo,
    const float* __restrict__ bias,
    const float* __restrict__ gamma, const float* __restrict__ beta,
    const float* __restrict__ mean, const float* __restrict__ var,
    float* __restrict__ outF, unsigned short* __restrict__ outHi,
    unsigned short* __restrict__ outLo) {
  __shared__ __attribute__((aligned(128))) char lds[32768];
  const int AHI = 0, ALO = 8192, BHI = 16384, BLO = 24576;

  int tid = threadIdx.x, wave = tid >> 6, lane = tid & 63;
  int wr = wave >> 1, wc = wave & 1;
  int m0 = blockIdx.x * 128, n0 = blockIdx.y * 128;
  int lr = lane & 15, lq = lane >> 4;

  f32x4 acc[4][4];
#pragma unroll
  for (int i = 0; i < 4; ++i)
#pragma unroll
    for (int j = 0; j < 4; ++j) acc[i][j] = (f32x4)0.f;

  for (int kt = 0; kt < 16; ++kt) {
    int kbase = kt * 32;
    bool first = kbase < 256;
    const unsigned short* Ah_ = first ? aHi : hHi;
    const unsigned short* Al_ = first ? aLo : hLo;
    const unsigned short* Bh_ = first ? wlHi : wrHi;
    const unsigned short* Bl_ = first ? wlLo : wrLo;
    int kh = (kbase & 255) + lq * 8;  // element offset in the 256-wide half

    // this wave stages sub-tiles {2*wave, 2*wave+1} of A and B, hi+lo
#pragma unroll
    for (int t = 0; t < 2; ++t) {
      int mi = wave * 2 + t;
      int gm = m0 + mi * 16 + lr;
      gm = gm < NN ? gm : NN - 1;
      gload_lds16(Ah_ + (size_t)gm * DD + kh, &lds[AHI + mi * 1024]);
      gload_lds16(Al_ + (size_t)gm * DD + kh, &lds[ALO + mi * 1024]);
      int gn = n0 + mi * 16 + lr;
      gload_lds16(Bh_ + (size_t)gn * DD + kh, &lds[BHI + mi * 1024]);
      gload_lds16(Bl_ + (size_t)gn * DD + kh, &lds[BLO + mi * 1024]);
    }
    __syncthreads();

    bf16x8s fbhi[4], fblo[4];
#pragma unroll
    for (int j = 0; j < 4; ++j) {
      int offb = (wc * 4 + j) * 1024 + lane * 16;
      fbhi[j] = *reinterpret_cast<const bf16x8s*>(&lds[BHI + offb]);
      fblo[j] = *reinterpret_cast<const bf16x8s*>(&lds[BLO + offb]);
    }
#pragma unroll
    for (int i = 0; i < 4; ++i) {
      int offa = (wr * 4 + i) * 1024 + lane * 16;
      bf16x8s fahi = *reinterpret_cast<const bf16x8s*>(&lds[AHI + offa]);
      bf16x8s falo = *reinterpret_cast<const bf16x8s*>(&lds[ALO + offa]);
#pragma unroll
      for (int j = 0; j < 4; ++j) {
        mfma_bf16(fahi, fbhi[j], acc[i][j]);
        mfma_bf16(fahi, fblo[j], acc[i][j]);
        mfma_bf16(falo, fbhi[j], acc[i][j]);
      }
    }
    __syncthreads();
  }

  // epilogue: bias (+BN+ReLU+residual, re-split hi/lo) or fp32 store
#pragma unroll
  for (int j = 0; j < 4; ++j) {
    int n = n0 + wc * 64 + j * 16 + lr;
    float bb = bias[n], sc = 0.f, sh = 0.f;
    if (DO_BN) {
      float s = gamma[n] * rsqrtf(var[n] + EPSV);
      sc = s;
      sh = beta[n] - mean[n] * s;
    }
#pragma unroll
    for (int i = 0; i < 4; ++i) {
#pragma unroll
      for (int r = 0; r < 4; ++r) {
        int m = m0 + wr * 64 + i * 16 + lq * 4 + r;
        if (m < NN) {
          float v = acc[i][j][r] + bb;
          size_t idx = (size_t)m * DD + n;
          if (DO_BN) {
            v = fmaxf(v * sc + sh, 0.f);
            v += bf2f(hHi[idx]) + bf2f(hLo[idx]);  // residual (exact reconstruct)
            unsigned short h = f2bf(v);
            outHi[idx] = h;
            outLo[idx] = f2bf(v - bf2f(h));
          } else {
            outF[idx] = v;
          }
        }
      }
    }
  }
}

// ---------------- launch ----------------

extern "C" void kernel_launch(void* const* d_in, const int* in_sizes, int n_in,
                              void* d_out, int out_size, void* d_ws, size_t ws_size,
                              hipStream_t stream) {
  const float* x   = (const float*)d_in[0];
  const int*   ei  = (const int*)d_in[1];
  const float* Wl[3] = {(const float*)d_in[2], (const float*)d_in[5], (const float*)d_in[8]};
  const float* Wr[3] = {(const float*)d_in[3], (const float*)d_in[6], (const float*)d_in[9]};
  const float* bs[3] = {(const float*)d_in[4], (const float*)d_in[7], (const float*)d_in[10]};
  const float* g0  = (const float*)d_in[11];
  const float* be0 = (const float*)d_in[12];
  const float* mu0 = (const float*)d_in[13];
  const float* va0 = (const float*)d_in[14];
  const float* g1  = (const float*)d_in[15];
  const float* be1 = (const float*)d_in[16];
  const float* mu1 = (const float*)d_in[17];
  const float* va1 = (const float*)d_in[18];
  float* out = (float*)d_out;

  char* w = (char*)d_ws;
  const size_t o_deg    = 0;
  const size_t o_rowptr = 262144;
  const size_t o_cursor = 524288;
  const size_t o_colidx = 786432;     // 3.2 MB
  const size_t o_deginv = 4194304;
  const size_t o_bsum   = 4456448;
  const size_t o_boff   = 4460544;
  const size_t o_wt     = 4464640;    // 12 planes * 131072 B
  const size_t PLANE    = (size_t)NN * DD * 2;  // 25.6 MB
  const size_t o_xhi    = 6291456;
  const size_t o_xlo    = o_xhi + PLANE;
  const size_t o_h1hi   = o_xhi + 2 * PLANE;
  const size_t o_h1lo   = o_xhi + 3 * PLANE;
  const size_t o_agghi  = o_xhi + 4 * PLANE;
  const size_t o_agglo  = o_xhi + 5 * PLANE;   // total ~160 MB

  int*   deg     = (int*)(w + o_deg);
  int*   row_ptr = (int*)(w + o_rowptr);
  int*   cursor  = (int*)(w + o_cursor);
  int*   col_idx = (int*)(w + o_colidx);
  float* deg_inv = (float*)(w + o_deginv);
  int*   bsum    = (int*)(w + o_bsum);
  int*   boff    = (int*)(w + o_boff);
  unsigned short* wt    = (unsigned short*)(w + o_wt);
  unsigned short* xhi   = (unsigned short*)(w + o_xhi);
  unsigned short* xlo   = (unsigned short*)(w + o_xlo);
  unsigned short* h1hi  = (unsigned short*)(w + o_h1hi);
  unsigned short* h1lo  = (unsigned short*)(w + o_h1lo);
  unsigned short* agghi = (unsigned short*)(w + o_agghi);
  unsigned short* agglo = (unsigned short*)(w + o_agglo);

  // per-layer W^T planes: [l]: WlT_hi, WlT_lo, WrT_hi, WrT_lo (65536 elems each)
  unsigned short* wlT[3][2];
  unsigned short* wrT[3][2];
  for (int l = 0; l < 3; ++l) {
    wlT[l][0] = wt + (size_t)(4 * l + 0) * 65536;
    wlT[l][1] = wt + (size_t)(4 * l + 1) * 65536;
    wrT[l][0] = wt + (size_t)(4 * l + 2) * 65536;
    wrT[l][1] = wt + (size_t)(4 * l + 3) * 65536;
  }

  const int SCAN_BLOCKS = (NN + 1023) / 1024;  // 49

  // ---- CSR build ----
  hipMemsetAsync(deg, 0, NN * sizeof(int), stream);
  deg_count_k<<<NE / 256, 256, 0, stream>>>(ei, deg);
  scan1_k<<<SCAN_BLOCKS, 1024, 0, stream>>>(deg, row_ptr, bsum);
  scan2_k<<<1, 64, 0, stream>>>(bsum, boff, row_ptr, SCAN_BLOCKS);
  scan3_k<<<SCAN_BLOCKS, 1024, 0, stream>>>(row_ptr, boff, deg, deg_inv);
  hipMemcpyAsync(cursor, row_ptr, NN * sizeof(int), hipMemcpyDeviceToDevice, stream);
  csr_fill_k<<<NE / 256, 256, 0, stream>>>(ei, cursor, col_idx);

  // ---- precompute bf16 hi/lo forms ----
  split_x_k<<<NN * DD / 4 / 256, 256, 0, stream>>>(x, xhi, xlo);
  for (int l = 0; l < 3; ++l) {
    wtprep_k<<<64, 256, 0, stream>>>(Wl[l], wlT[l][0], wlT[l][1]);
    wtprep_k<<<64, 256, 0, stream>>>(Wr[l], wrT[l][0], wrT[l][1]);
  }

  dim3 ggrid((NN + 127) / 128, 2);  // 391 x 2

  // ---- layer 0: x -> h1 ----
  sage_agg_k<<<NN / 4, 256, 0, stream>>>(xhi, xlo, row_ptr, col_idx, deg_inv, agghi, agglo);
  sage_gemm_k<true><<<ggrid, 256, 0, stream>>>(agghi, agglo, xhi, xlo,
                                               wlT[0][0], wlT[0][1], wrT[0][0], wrT[0][1],
                                               bs[0], g0, be0, mu0, va0,
                                               nullptr, h1hi, h1lo);
  // ---- layer 1: h1 -> h2 (reuses x planes) ----
  sage_agg_k<<<NN / 4, 256, 0, stream>>>(h1hi, h1lo, row_ptr, col_idx, deg_inv, agghi, agglo);
  sage_gemm_k<true><<<ggrid, 256, 0, stream>>>(agghi, agglo, h1hi, h1lo,
                                               wlT[1][0], wlT[1][1], wrT[1][0], wrT[1][1],
                                               bs[1], g1, be1, mu1, va1,
                                               nullptr, xhi, xlo);
  // ---- layer 2: h2 -> out (fp32) ----
  sage_agg_k<<<NN / 4, 256, 0, stream>>>(xhi, xlo, row_ptr, col_idx, deg_inv, agghi, agglo);
  sage_gemm_k<false><<<ggrid, 256, 0, stream>>>(agghi, agglo, xhi, xlo,
                                                wlT[2][0], wlT[2][1], wrT[2][0], wrT[2][1],
                                                bs[2], nullptr, nullptr, nullptr, nullptr,
                                                out, nullptr, nullptr);
}